// Round 7
// baseline (277.288 us; speedup 1.0000x reference)
//
#include <hip/hip_runtime.h>
#include <hip/hip_bf16.h>

// GLM flash attention fwd: b=2, s=2048, nh=16, hs=64, fp32 I/O, bf16 MFMA.
// R14 = R13 body with the register budget PINNED. R13's launch_bounds(64,4)
// sets only a MIN waves/EU; the scheduler pursued 8 waves/SIMD anyway,
// squeezing to 64 VGPRs by serializing all loads (no spill, but prefetch
// destroyed: MfmaUtil 4.5%, fa 196us). Fix: amdgpu_waves_per_eu(4,4) --
// the max=4 stops the occupancy chase, giving the full 128-VGPR budget
// (512-reg pool / 4) so the carried-K prefetch and chunk-top V loads stay
// in flight. Grid 4096 one-wave blocks = 16 waves/CU = exactly 4/SIMD.
// Structure: no split-K, no atomics; one wave owns 16 q-rows over the full
// k-range, normalizes in-register, single plain store. LPT order. P tile
// in LDS (2.5KB, kh-double-buffered, one lgkm drain/chunk). 2 dispatches.

typedef __attribute__((ext_vector_type(8))) __bf16 bf16x8;
typedef __attribute__((ext_vector_type(4))) __bf16 bf16x4;
typedef __attribute__((ext_vector_type(4))) float floatx4;

#define S_LEN 2048
#define NH 16
#define HS 64
#define RS 1024                     // fp32 floats between seq positions
#define KB_ELEMS (2 * NH * S_LEN * HS)   // 4,194,304 bf16 = 8 MB
#define SCALE_LOG2E 0.18033688011112042f // 0.125 / ln(2)

#if __has_builtin(__builtin_amdgcn_exp2f)
#define EXP2(x) __builtin_amdgcn_exp2f(x)
#else
#define EXP2(x) exp2f(x)
#endif

#define MFMA(a, b, c) __builtin_amdgcn_mfma_f32_16x16x32_bf16(a, b, c, 0, 0, 0)

// ---- pre-pass: K -> bf16 [b,h,s,d] (scaled), V -> bf16 V^T [b,h,d,s] ----
__global__ __launch_bounds__(256) void conv_kv(const float* __restrict__ k,
                                               const float* __restrict__ v,
                                               __bf16* __restrict__ kbuf,
                                               __bf16* __restrict__ vbuf)
{
    __shared__ __align__(16) __bf16 tile[64][72];     // [d][s], 144B rows
    const int tid = threadIdx.x;

    const int bh = blockIdx.x >> 5;                   // 32 s-tiles per (b,h)
    const int st = blockIdx.x & 31;
    const int b = bh >> 4, h = bh & 15;
    const int s0 = st * 64;

#pragma unroll
    for (int it = 0; it < 4; ++it) {
        const int idx = it * 256 + tid;
        const int s = idx >> 4, f4 = idx & 15;
        floatx4 val = *(const floatx4*)(k + ((size_t)(b * 2048 + s0 + s)) * 1024 + h * 64 + f4 * 4);
        bf16x4 w;
        w[0] = (__bf16)(val[0] * SCALE_LOG2E); w[1] = (__bf16)(val[1] * SCALE_LOG2E);
        w[2] = (__bf16)(val[2] * SCALE_LOG2E); w[3] = (__bf16)(val[3] * SCALE_LOG2E);
        *(bf16x4*)(kbuf + ((size_t)((b * 16 + h) * 2048 + s0 + s)) * 64 + f4 * 4) = w;
    }

#pragma unroll
    for (int it = 0; it < 4; ++it) {
        const int idx = it * 256 + tid;
        const int s = idx >> 4, f4 = idx & 15;
        floatx4 val = *(const floatx4*)(v + ((size_t)(b * 2048 + s0 + s)) * 1024 + h * 64 + f4 * 4);
#pragma unroll
        for (int i = 0; i < 4; ++i)
            tile[f4 * 4 + i][s] = (__bf16)val[i];
    }
    __syncthreads();
#pragma unroll
    for (int it = 0; it < 2; ++it) {
        const int idx = it * 256 + tid;
        const int d = idx >> 3, sg = idx & 7;
        bf16x8 w = *(const bf16x8*)&tile[d][sg * 8];
        *(bf16x8*)(vbuf + ((size_t)((b * 16 + h) * 64 + d)) * 2048 + s0 + sg * 8) = w;
    }
}

// ---- main kernel: 1 wave per block, 16 q-rows, full k-range, no atomics ----
__global__ __launch_bounds__(64) __attribute__((amdgpu_waves_per_eu(4, 4)))
void fa_part9(
    const float* __restrict__ q, const __bf16* __restrict__ kb,
    const __bf16* __restrict__ vt, const int* __restrict__ glm_mask,
    float* __restrict__ out)
{
    __shared__ __align__(16) __bf16 pt[2][16 * 40];  // 2560 B

    const int lane = threadIdx.x;                 // one wave per block
    const int col  = lane & 15, quad = lane >> 4;

    // LPT order: longest q-tiles first (q0 descending), heads fastest
    const int tile = blockIdx.x >> 5;             // 0..127
    const int head = blockIdx.x & 31;
    const int b = head >> 4, h = head & 15;
    const int q0 = (127 - tile) * 16;             // this wave's 16 q-rows

    const int bp = glm_mask[b];
    int klen = q0 + 16; if (bp > klen) klen = bp;
    const int nch = (klen + 63) >> 6;             // >= 1 always

    const __bf16* kbh = kb + ((size_t)(b * 16 + h)) * (2048 * 64);
    const __bf16* vth = vt + ((size_t)(b * 16 + h)) * (64 * 2048);
    const size_t obase = (size_t)b * (S_LEN * RS) + h * HS;

    // Q A-frag: aq[half], kd = half*32 + quad*8 + j; row = q0+col
    bf16x8 aq[2];
    {
        const float* qp = q + obase + (size_t)(q0 + col) * RS + quad * 8;
        floatx4 a0 = *(const floatx4*)qp;
        floatx4 a1 = *(const floatx4*)(qp + 4);
        floatx4 a2 = *(const floatx4*)(qp + 32);
        floatx4 a3 = *(const floatx4*)(qp + 36);
#pragma unroll
        for (int i = 0; i < 4; ++i) {
            aq[0][i] = (__bf16)a0[i]; aq[0][4 + i] = (__bf16)a1[i];
            aq[1][i] = (__bf16)a2[i]; aq[1][4 + i] = (__bf16)a3[i];
        }
    }

    floatx4 o[4];                   // O C-frags: row = q0+quad*4+r, d = f*16+col
    float ls[4];
#pragma unroll
    for (int f = 0; f < 4; ++f) o[f] = (floatx4){0.f, 0.f, 0.f, 0.f};
#pragma unroll
    for (int r = 0; r < 4; ++r) ls[r] = 0.f;

    // preload chunk 0's K frags (single carried buffer)
    bf16x8 bk[4][2];
#pragma unroll
    for (int kg = 0; kg < 4; ++kg)
#pragma unroll
        for (int hf = 0; hf < 2; ++hf)
            bk[kg][hf] = *(const bf16x8*)(kbh + (size_t)(kg * 16 + col) * 64 + hf * 32 + quad * 8);

    for (int c = 0; c < nch; ++c) {
        const int k0 = c * 64;

        // V B-frags for this chunk (consumed in PV; QK+exp covers latency)
        bf16x8 bv[4][2];
#pragma unroll
        for (int f = 0; f < 4; ++f)
#pragma unroll
            for (int kh = 0; kh < 2; ++kh)
                bv[f][kh] = *(const bf16x8*)(vth + (size_t)(f * 16 + col) * 2048 + k0 + kh * 32 + quad * 8);

        // QK^T (K carries 0.125*log2e): 8 MFMAs
        floatx4 z = {0.f, 0.f, 0.f, 0.f};
        floatx4 s[4];
        __builtin_amdgcn_s_setprio(1);
#pragma unroll
        for (int kg = 0; kg < 4; ++kg) {
            s[kg] = MFMA(aq[0], bk[kg][0], z);
            s[kg] = MFMA(aq[1], bk[kg][1], s[kg]);
        }
        __builtin_amdgcn_s_setprio(0);

        // overwrite bk with next chunk's K frags (used ~exp+drain+PV later)
        if (c + 1 < nch) {
#pragma unroll
            for (int kg = 0; kg < 4; ++kg)
#pragma unroll
                for (int hf = 0; hf < 2; ++hf)
                    bk[kg][hf] = *(const bf16x8*)(kbh + (size_t)(k0 + 64 + kg * 16 + col) * 64 + hf * 32 + quad * 8);
        }

        // exp + mask -> both kh P tiles, then ONE lgkm drain
#pragma unroll
        for (int kh = 0; kh < 2; ++kh) {
            __bf16* pw = &pt[kh][0];
#pragma unroll
            for (int g2 = 0; g2 < 2; ++g2) {
                const int kj = k0 + (kh * 2 + g2) * 16 + col;
                const bool pre = kj < bp;
#pragma unroll
                for (int r = 0; r < 4; ++r) {
                    const int qi = q0 + quad * 4 + r;
                    float e = EXP2(s[kh * 2 + g2][r]);
                    float p = (pre || (kj <= qi)) ? e : 0.f;
                    ls[r] += p;
                    pw[(quad * 4 + r) * 40 + g2 * 16 + col] = (__bf16)p;
                }
            }
        }
        __asm__ __volatile__("" ::: "memory");
        __builtin_amdgcn_s_waitcnt(0xC07F);   // lgkmcnt(0): P writes drained
        __asm__ __volatile__("" ::: "memory");

        // PV: 8 MFMAs
        __builtin_amdgcn_s_setprio(1);
#pragma unroll
        for (int kh = 0; kh < 2; ++kh) {
            bf16x8 ap = *(const bf16x8*)(&pt[kh][0] + col * 40 + quad * 8);
#pragma unroll
            for (int f = 0; f < 4; ++f)
                o[f] = MFMA(ap, bv[f][kh], o[f]);
        }
        __builtin_amdgcn_s_setprio(0);
        __asm__ __volatile__("" ::: "memory");  // next P writes stay behind ap reads
    }

    // epilogue: reduce l across the 16 col-lanes, normalize, plain stores
#pragma unroll
    for (int r = 0; r < 4; ++r) {
        float l = ls[r];
        l += __shfl_xor(l, 1);
        l += __shfl_xor(l, 2);
        l += __shfl_xor(l, 4);
        l += __shfl_xor(l, 8);
        const float inv = (l > 0.f) ? (1.f / l) : 0.f;
        const int row = q0 + quad * 4 + r;
        float* op = out + obase + (size_t)row * RS;
#pragma unroll
        for (int f = 0; f < 4; ++f)
            op[f * 16 + col] = o[f][r] * inv;
    }
}

extern "C" void kernel_launch(void* const* d_in, const int* in_sizes, int n_in,
                              void* d_out, int out_size, void* d_ws, size_t ws_size,
                              hipStream_t stream) {
    const float* q = (const float*)d_in[0];
    const float* k = (const float*)d_in[1];
    const float* v = (const float*)d_in[2];
    const int* glm = (const int*)d_in[3];
    float* out     = (float*)d_out;

    const size_t kb_bytes = (size_t)KB_ELEMS * 2;            // 8 MB
    __bf16* kbuf = (__bf16*)d_ws;
    __bf16* vbuf = (__bf16*)((char*)d_ws + kb_bytes);

    hipLaunchKernelGGL(conv_kv, dim3(1024), dim3(256), 0, stream,
                       k, v, kbuf, vbuf);
    // 128 q-tiles (LPT order) x 32 heads = 4096 one-wave blocks
    hipLaunchKernelGGL(fa_part9, dim3(4096), dim3(64), 0, stream,
                       q, kbuf, vbuf, glm, out);
}

// Round 8
// 174.084 us; speedup vs baseline: 1.5928x; 1.5928x over previous
//
#include <hip/hip_runtime.h>
#include <hip/hip_bf16.h>

// GLM flash attention fwd: b=2, s=2048, nh=16, hs=64, fp32 I/O, bf16 MFMA.
// R15: defeat load-sinking with global_load_lds. R12-R14 all bottomed out at
// ~8K cyc per 64-col chunk = ~32 serialized L2 round trips: the compiler
// sinks register-destined global loads to their uses (R13/R14 proved it,
// VGPR squeezed to 64 both times). global_load_lds has NO VGPR destination
// -> cannot be sunk; 16 DMA loads/chunk sit in the vmcnt queue while the
// wave computes. Blocks stay ONE wave (LDS is wave-private, zero barriers).
// Double-buffered K(8KB)+V(8KB) per chunk, LDS dest linear, global source
// pre-swizzled granule^=((row&7)<<4) and the same XOR applied on frag
// ds_read_b128 (rule #21) -> no 8-way stride-128B conflicts. 32 q-rows per
// wave (R12 tiling), 2048 blocks, LDS 37KB -> 4 blocks/CU (1 wave/SIMD,
// LDS-capped, full VGPR budget). Explicit s_waitcnt vmcnt(0) at chunk top
// is the only memory stall. No split-K, no atomics, in-register normalize.

typedef __attribute__((ext_vector_type(8))) __bf16 bf16x8;
typedef __attribute__((ext_vector_type(4))) __bf16 bf16x4;
typedef __attribute__((ext_vector_type(4))) float floatx4;

#define S_LEN 2048
#define NH 16
#define HS 64
#define RS 1024                     // fp32 floats between seq positions
#define KB_ELEMS (2 * NH * S_LEN * HS)   // 4,194,304 bf16 = 8 MB
#define SCALE_LOG2E 0.18033688011112042f // 0.125 / ln(2)

#if __has_builtin(__builtin_amdgcn_exp2f)
#define EXP2(x) __builtin_amdgcn_exp2f(x)
#else
#define EXP2(x) exp2f(x)
#endif

#define MFMA(a, b, c) __builtin_amdgcn_mfma_f32_16x16x32_bf16(a, b, c, 0, 0, 0)

// async 16B global->LDS (no VGPR destination; vmcnt-counted)
#define GLOAD16(GP, LP)                                                        \
  __builtin_amdgcn_global_load_lds(                                            \
      (const __attribute__((address_space(1))) void*)(GP),                     \
      (__attribute__((address_space(3))) void*)(LP), 16, 0, 0)

// ---- pre-pass: K -> bf16 [b,h,s,d] (scaled), V -> bf16 V^T [b,h,d,s] ----
__global__ __launch_bounds__(256) void conv_kv(const float* __restrict__ k,
                                               const float* __restrict__ v,
                                               __bf16* __restrict__ kbuf,
                                               __bf16* __restrict__ vbuf)
{
    __shared__ __align__(16) __bf16 tile[64][72];     // [d][s], 144B rows
    const int tid = threadIdx.x;

    const int bh = blockIdx.x >> 5;                   // 32 s-tiles per (b,h)
    const int st = blockIdx.x & 31;
    const int b = bh >> 4, h = bh & 15;
    const int s0 = st * 64;

#pragma unroll
    for (int it = 0; it < 4; ++it) {
        const int idx = it * 256 + tid;
        const int s = idx >> 4, f4 = idx & 15;
        floatx4 val = *(const floatx4*)(k + ((size_t)(b * 2048 + s0 + s)) * 1024 + h * 64 + f4 * 4);
        bf16x4 w;
        w[0] = (__bf16)(val[0] * SCALE_LOG2E); w[1] = (__bf16)(val[1] * SCALE_LOG2E);
        w[2] = (__bf16)(val[2] * SCALE_LOG2E); w[3] = (__bf16)(val[3] * SCALE_LOG2E);
        *(bf16x4*)(kbuf + ((size_t)((b * 16 + h) * 2048 + s0 + s)) * 64 + f4 * 4) = w;
    }

#pragma unroll
    for (int it = 0; it < 4; ++it) {
        const int idx = it * 256 + tid;
        const int s = idx >> 4, f4 = idx & 15;
        floatx4 val = *(const floatx4*)(v + ((size_t)(b * 2048 + s0 + s)) * 1024 + h * 64 + f4 * 4);
#pragma unroll
        for (int i = 0; i < 4; ++i)
            tile[f4 * 4 + i][s] = (__bf16)val[i];
    }
    __syncthreads();
#pragma unroll
    for (int it = 0; it < 2; ++it) {
        const int idx = it * 256 + tid;
        const int d = idx >> 3, sg = idx & 7;
        bf16x8 w = *(const bf16x8*)&tile[d][sg * 8];
        *(bf16x8*)(vbuf + ((size_t)((b * 16 + h) * 64 + d)) * 2048 + s0 + sg * 8) = w;
    }
}

// ---- main kernel: 1 wave/block, 32 q-rows, LDS-staged K/V via DMA ----
__global__ __launch_bounds__(64, 1) void fa_part10(
    const float* __restrict__ q, const __bf16* __restrict__ kb,
    const __bf16* __restrict__ vt, const int* __restrict__ glm_mask,
    float* __restrict__ out)
{
    __shared__ __align__(16) __bf16 ldsK[2][64 * 64];   // 8KB per buf, linear
    __shared__ __align__(16) __bf16 ldsV[2][64 * 64];   // 8KB per buf, linear
    __shared__ __align__(16) __bf16 pt[2][2][16 * 40];  // [kh][rg], 5KB

    const int lane = threadIdx.x;                 // one wave per block
    const int col  = lane & 15, quad = lane >> 4;

    // LPT order: longest q-tiles first (q0 descending), heads fastest
    const int tile = blockIdx.x >> 5;             // 0..63
    const int head = blockIdx.x & 31;
    const int b = head >> 4, h = head & 15;
    const int q0 = (63 - tile) * 32;              // this wave's 32 q-rows

    const int bp = glm_mask[b];
    int klen = q0 + 32; if (bp > klen) klen = bp;
    const int nch = (klen + 63) >> 6;             // 1..32

    const __bf16* kbh = kb + ((size_t)(b * 16 + h)) * (2048 * 64);
    const __bf16* vth = vt + ((size_t)(b * 16 + h)) * (64 * 2048);
    const size_t obase = (size_t)b * (S_LEN * RS) + h * HS;

    // staging lane geometry: load i covers 8 rows x 128B; this lane handles
    // row (i*8 + rowi), 16B granule (lane&7), with source-side XOR swizzle.
    const int rowi = lane >> 3;                   // 0..7
    const int gswz = ((lane & 7) ^ rowi) << 4;    // source granule byte offset

#define STAGE_CHUNK(K0, NB)                                                    \
  {                                                                            \
    const char* gk = (const char*)kbh + (size_t)(K0) * 128;                    \
    const char* gv = (const char*)vth + (size_t)(K0) * 2;                      \
    _Pragma("unroll")                                                          \
    for (int i = 0; i < 8; ++i) {                                              \
      GLOAD16(gk + (size_t)(i * 8 + rowi) * 128 + gswz, &ldsK[NB][i * 512]);   \
      GLOAD16(gv + (size_t)(i * 8 + rowi) * 4096 + gswz, &ldsV[NB][i * 512]);  \
    }                                                                          \
  }

    // Q A-frags: aq[rg][half], kd = half*32 + quad*8 + j
    bf16x8 aq[2][2];
#pragma unroll
    for (int rg = 0; rg < 2; ++rg) {
        const float* qp = q + obase + (size_t)(q0 + rg * 16 + col) * RS + quad * 8;
        floatx4 a0 = *(const floatx4*)qp;
        floatx4 a1 = *(const floatx4*)(qp + 4);
        floatx4 a2 = *(const floatx4*)(qp + 32);
        floatx4 a3 = *(const floatx4*)(qp + 36);
#pragma unroll
        for (int i = 0; i < 4; ++i) {
            aq[rg][0][i] = (__bf16)a0[i]; aq[rg][0][4 + i] = (__bf16)a1[i];
            aq[rg][1][i] = (__bf16)a2[i]; aq[rg][1][4 + i] = (__bf16)a3[i];
        }
    }

    floatx4 o[2][4];                // O C-frags: row = q0+rg*16+quad*4+r, d = f*16+col
    float ls[2][4];
#pragma unroll
    for (int rg = 0; rg < 2; ++rg)
#pragma unroll
        for (int f = 0; f < 4; ++f) {
            o[rg][f] = (floatx4){0.f, 0.f, 0.f, 0.f};
            ls[rg][f] = 0.f;
        }

    STAGE_CHUNK(0, 0);              // prologue: chunk 0 in flight

    const int cswz = (col & 7) << 4;   // read-side XOR (row&7)<<4, row=.*16+col

    for (int c = 0; c < nch; ++c) {
        const int k0 = c * 64;
        const int cur = c & 1;

        // staged data for chunk c guaranteed landed after this
        __asm__ __volatile__("s_waitcnt vmcnt(0)" ::: "memory");

        // fragment reads from linear-but-swizzled LDS tiles
        const char* lK = (const char*)&ldsK[cur][0];
        const char* lV = (const char*)&ldsV[cur][0];
        bf16x8 bk[4][2], bv[4][2];
#pragma unroll
        for (int kg = 0; kg < 4; ++kg)
#pragma unroll
            for (int hf = 0; hf < 2; ++hf)
                bk[kg][hf] = *(const bf16x8*)(lK + (kg * 16 + col) * 128 + ((hf * 64 + quad * 16) ^ cswz));
#pragma unroll
        for (int f = 0; f < 4; ++f)
#pragma unroll
            for (int kh = 0; kh < 2; ++kh)
                bv[f][kh] = *(const bf16x8*)(lV + (f * 16 + col) * 128 + ((kh * 64 + quad * 16) ^ cswz));

        // issue chunk c+1's DMA into the other buffer (in flight during compute)
        if (c + 1 < nch)
            STAGE_CHUNK(k0 + 64, cur ^ 1);

        // QK^T (K carries 0.125*log2e): 16 MFMAs
        floatx4 z = {0.f, 0.f, 0.f, 0.f};
        floatx4 s[2][4];
        __builtin_amdgcn_s_setprio(1);
#pragma unroll
        for (int rg = 0; rg < 2; ++rg)
#pragma unroll
            for (int kg = 0; kg < 4; ++kg) {
                s[rg][kg] = MFMA(aq[rg][0], bk[kg][0], z);
                s[rg][kg] = MFMA(aq[rg][1], bk[kg][1], s[rg][kg]);
            }
        __builtin_amdgcn_s_setprio(0);

        // exp + mask -> both kh P tiles, then ONE lgkm drain
#pragma unroll
        for (int kh = 0; kh < 2; ++kh) {
#pragma unroll
            for (int rg = 0; rg < 2; ++rg) {
                __bf16* pw = &pt[kh][rg][0];
#pragma unroll
                for (int g2 = 0; g2 < 2; ++g2) {
                    const int kj = k0 + (kh * 2 + g2) * 16 + col;
                    const bool pre = kj < bp;
#pragma unroll
                    for (int r = 0; r < 4; ++r) {
                        const int qi = q0 + rg * 16 + quad * 4 + r;
                        float e = EXP2(s[rg][kh * 2 + g2][r]);
                        float p = (pre || (kj <= qi)) ? e : 0.f;
                        ls[rg][r] += p;
                        pw[(quad * 4 + r) * 40 + g2 * 16 + col] = (__bf16)p;
                    }
                }
            }
        }
        __asm__ __volatile__("" ::: "memory");
        __builtin_amdgcn_s_waitcnt(0xC07F);   // lgkmcnt(0): P writes drained
        __asm__ __volatile__("" ::: "memory");

        // PV: 16 MFMAs
        __builtin_amdgcn_s_setprio(1);
#pragma unroll
        for (int kh = 0; kh < 2; ++kh)
#pragma unroll
            for (int rg = 0; rg < 2; ++rg) {
                bf16x8 ap = *(const bf16x8*)(&pt[kh][rg][0] + col * 40 + quad * 8);
#pragma unroll
                for (int f = 0; f < 4; ++f)
                    o[rg][f] = MFMA(ap, bv[f][kh], o[rg][f]);
            }
        __builtin_amdgcn_s_setprio(0);
        __asm__ __volatile__("" ::: "memory");  // next P writes stay behind ap reads
    }

    // epilogue: reduce l across the 16 col-lanes, normalize, plain stores
#pragma unroll
    for (int rg = 0; rg < 2; ++rg)
#pragma unroll
        for (int r = 0; r < 4; ++r) {
            float l = ls[rg][r];
            l += __shfl_xor(l, 1);
            l += __shfl_xor(l, 2);
            l += __shfl_xor(l, 4);
            l += __shfl_xor(l, 8);
            const float inv = (l > 0.f) ? (1.f / l) : 0.f;
            const int row = q0 + rg * 16 + quad * 4 + r;
            float* op = out + obase + (size_t)row * RS;
#pragma unroll
            for (int f = 0; f < 4; ++f)
                op[f * 16 + col] = o[rg][f][r] * inv;
        }
}

extern "C" void kernel_launch(void* const* d_in, const int* in_sizes, int n_in,
                              void* d_out, int out_size, void* d_ws, size_t ws_size,
                              hipStream_t stream) {
    const float* q = (const float*)d_in[0];
    const float* k = (const float*)d_in[1];
    const float* v = (const float*)d_in[2];
    const int* glm = (const int*)d_in[3];
    float* out     = (float*)d_out;

    const size_t kb_bytes = (size_t)KB_ELEMS * 2;            // 8 MB
    __bf16* kbuf = (__bf16*)d_ws;
    __bf16* vbuf = (__bf16*)((char*)d_ws + kb_bytes);

    hipLaunchKernelGGL(conv_kv, dim3(1024), dim3(256), 0, stream,
                       k, v, kbuf, vbuf);
    // 64 q-tiles (LPT order) x 32 heads = 2048 one-wave blocks
    hipLaunchKernelGGL(fa_part10, dim3(2048), dim3(64), 0, stream,
                       q, kbuf, vbuf, glm, out);
}

// Round 9
// 173.746 us; speedup vs baseline: 1.5959x; 1.0019x over previous
//
#include <hip/hip_runtime.h>
#include <hip/hip_bf16.h>

// GLM flash attention fwd: b=2, s=2048, nh=16, hs=64, fp32 I/O, bf16 MFMA.
// R16: R15's DMA-staged pipeline + 2 waves/block sharing the staged K/V.
// R15 proved global_load_lds defeats load-sinking (VGPR 132, no spill,
// fa 93.6us) but ran 1 wave/SIMD -> zero TLP, ~4K cyc/chunk of unhidden
// latency (MfmaUtil 9.3%, Occ 8.3%). Now each wave owns 16 q-rows of the
// block's 32-row tile and stages HALF the chunk (4K+4V DMA loads); LDS
// 34.6KB (pt single-buffer/wave, 2 lgkm drains/chunk) -> 4 blocks/CU
// = 2 waves/SIMD. nch is block-uniform (klen from the q-tile) so the one
// __syncthreads per chunk (= the vmcnt(0)+barrier rendezvous shared
// staging needs anyway) is legal. Staging/read XOR swizzle carried
// verbatim from R15 (bank-conflict counter-verified). No split-K, no
// atomics, in-register normalize, single plain store. 2 dispatches.

typedef __attribute__((ext_vector_type(8))) __bf16 bf16x8;
typedef __attribute__((ext_vector_type(4))) __bf16 bf16x4;
typedef __attribute__((ext_vector_type(4))) float floatx4;

#define S_LEN 2048
#define NH 16
#define HS 64
#define RS 1024                     // fp32 floats between seq positions
#define KB_ELEMS (2 * NH * S_LEN * HS)   // 4,194,304 bf16 = 8 MB
#define SCALE_LOG2E 0.18033688011112042f // 0.125 / ln(2)

#if __has_builtin(__builtin_amdgcn_exp2f)
#define EXP2(x) __builtin_amdgcn_exp2f(x)
#else
#define EXP2(x) exp2f(x)
#endif

#define MFMA(a, b, c) __builtin_amdgcn_mfma_f32_16x16x32_bf16(a, b, c, 0, 0, 0)

// async 16B global->LDS (no VGPR destination; vmcnt-counted)
#define GLOAD16(GP, LP)                                                        \
  __builtin_amdgcn_global_load_lds(                                            \
      (const __attribute__((address_space(1))) void*)(GP),                     \
      (__attribute__((address_space(3))) void*)(LP), 16, 0, 0)

// ---- pre-pass: K -> bf16 [b,h,s,d] (scaled), V -> bf16 V^T [b,h,d,s] ----
__global__ __launch_bounds__(256) void conv_kv(const float* __restrict__ k,
                                               const float* __restrict__ v,
                                               __bf16* __restrict__ kbuf,
                                               __bf16* __restrict__ vbuf)
{
    __shared__ __align__(16) __bf16 tile[64][72];     // [d][s], 144B rows
    const int tid = threadIdx.x;

    const int bh = blockIdx.x >> 5;                   // 32 s-tiles per (b,h)
    const int st = blockIdx.x & 31;
    const int b = bh >> 4, h = bh & 15;
    const int s0 = st * 64;

#pragma unroll
    for (int it = 0; it < 4; ++it) {
        const int idx = it * 256 + tid;
        const int s = idx >> 4, f4 = idx & 15;
        floatx4 val = *(const floatx4*)(k + ((size_t)(b * 2048 + s0 + s)) * 1024 + h * 64 + f4 * 4);
        bf16x4 w;
        w[0] = (__bf16)(val[0] * SCALE_LOG2E); w[1] = (__bf16)(val[1] * SCALE_LOG2E);
        w[2] = (__bf16)(val[2] * SCALE_LOG2E); w[3] = (__bf16)(val[3] * SCALE_LOG2E);
        *(bf16x4*)(kbuf + ((size_t)((b * 16 + h) * 2048 + s0 + s)) * 64 + f4 * 4) = w;
    }

#pragma unroll
    for (int it = 0; it < 4; ++it) {
        const int idx = it * 256 + tid;
        const int s = idx >> 4, f4 = idx & 15;
        floatx4 val = *(const floatx4*)(v + ((size_t)(b * 2048 + s0 + s)) * 1024 + h * 64 + f4 * 4);
#pragma unroll
        for (int i = 0; i < 4; ++i)
            tile[f4 * 4 + i][s] = (__bf16)val[i];
    }
    __syncthreads();
#pragma unroll
    for (int it = 0; it < 2; ++it) {
        const int idx = it * 256 + tid;
        const int d = idx >> 3, sg = idx & 7;
        bf16x8 w = *(const bf16x8*)&tile[d][sg * 8];
        *(bf16x8*)(vbuf + ((size_t)((b * 16 + h) * 64 + d)) * 2048 + s0 + sg * 8) = w;
    }
}

// ---- main kernel: 2 waves/block, 16 q-rows each, shared DMA-staged K/V ----
__global__ __launch_bounds__(128, 2) void fa_part11(
    const float* __restrict__ q, const __bf16* __restrict__ kb,
    const __bf16* __restrict__ vt, const int* __restrict__ glm_mask,
    float* __restrict__ out)
{
    __shared__ __align__(16) __bf16 ldsK[2][64 * 64];   // 8KB/buf, linear rows
    __shared__ __align__(16) __bf16 ldsV[2][64 * 64];   // 8KB/buf, linear rows
    __shared__ __align__(16) __bf16 pt[2][16 * 40];     // [wave], reused per kh

    const int tid  = threadIdx.x;
    const int wave = tid >> 6, lane = tid & 63;
    const int col  = lane & 15, quad = lane >> 4;

    // LPT order: longest q-tiles first (q0 descending), heads fastest
    const int tile = blockIdx.x >> 5;             // 0..63
    const int head = blockIdx.x & 31;
    const int b = head >> 4, h = head & 15;
    const int q0b = (63 - tile) * 32;             // block's 32 q-rows
    const int q0  = q0b + wave * 16;              // this wave's 16 q-rows

    const int bp = glm_mask[b];
    int klen = q0b + 32; if (bp > klen) klen = bp;   // block-uniform
    const int nch = (klen + 63) >> 6;                // 1..32, uniform

    const __bf16* kbh = kb + ((size_t)(b * 16 + h)) * (2048 * 64);
    const __bf16* vth = vt + ((size_t)(b * 16 + h)) * (64 * 2048);
    const size_t obase = (size_t)b * (S_LEN * RS) + h * HS;

    // staging geometry: DMA instruction j covers 8 rows x 128B; wave w owns
    // j = w*4 + i. Lane handles row (j*8 + rowi), granule lane&7, with the
    // source-side XOR swizzle (R15-verified conflict-free).
    const int rowi = lane >> 3;                   // 0..7
    const int gswz = ((lane & 7) ^ rowi) << 4;    // source granule byte offset

#define STAGE(K0, NB)                                                          \
  {                                                                            \
    const char* gk = (const char*)kbh + (size_t)(K0) * 128;                    \
    const char* gv = (const char*)vth + (size_t)(K0) * 2;                      \
    _Pragma("unroll")                                                          \
    for (int i = 0; i < 4; ++i) {                                              \
      const int j = wave * 4 + i;                                              \
      GLOAD16(gk + (size_t)(j * 8 + rowi) * 128 + gswz, &ldsK[NB][j * 512]);   \
      GLOAD16(gv + (size_t)(j * 8 + rowi) * 4096 + gswz, &ldsV[NB][j * 512]);  \
    }                                                                          \
  }

    // Q A-frag: aq[half], kd = half*32 + quad*8 + j; row = q0+col
    bf16x8 aq[2];
    {
        const float* qp = q + obase + (size_t)(q0 + col) * RS + quad * 8;
        floatx4 a0 = *(const floatx4*)qp;
        floatx4 a1 = *(const floatx4*)(qp + 4);
        floatx4 a2 = *(const floatx4*)(qp + 32);
        floatx4 a3 = *(const floatx4*)(qp + 36);
#pragma unroll
        for (int i = 0; i < 4; ++i) {
            aq[0][i] = (__bf16)a0[i]; aq[0][4 + i] = (__bf16)a1[i];
            aq[1][i] = (__bf16)a2[i]; aq[1][4 + i] = (__bf16)a3[i];
        }
    }

    floatx4 o[4];                   // O C-frags: row = q0+quad*4+r, d = f*16+col
    float ls[4];
#pragma unroll
    for (int f = 0; f < 4; ++f) o[f] = (floatx4){0.f, 0.f, 0.f, 0.f};
#pragma unroll
    for (int r = 0; r < 4; ++r) ls[r] = 0.f;

    STAGE(0, 0);                    // prologue: chunk 0 in flight (both halves)
    __syncthreads();                // chunk 0 landed (drains vmcnt + barrier)

    const int cswz = (col & 7) << 4;   // read-side XOR, row&7 = col&7

    for (int c = 0; c < nch; ++c) {
        const int k0 = c * 64;
        const int cur = c & 1;

        // fragment reads from linear-but-swizzled LDS tiles
        const char* lK = (const char*)&ldsK[cur][0];
        const char* lV = (const char*)&ldsV[cur][0];
        bf16x8 bk[4][2], bv[4][2];
#pragma unroll
        for (int kg = 0; kg < 4; ++kg)
#pragma unroll
            for (int hf = 0; hf < 2; ++hf)
                bk[kg][hf] = *(const bf16x8*)(lK + (kg * 16 + col) * 128 + ((hf * 64 + quad * 16) ^ cswz));
#pragma unroll
        for (int f = 0; f < 4; ++f)
#pragma unroll
            for (int kh = 0; kh < 2; ++kh)
                bv[f][kh] = *(const bf16x8*)(lV + (f * 16 + col) * 128 + ((kh * 64 + quad * 16) ^ cswz));

        // issue chunk c+1's DMA into the other buffer (in flight all chunk)
        if (c + 1 < nch)
            STAGE(k0 + 64, cur ^ 1);

        // QK^T (K carries 0.125*log2e): 8 MFMAs
        floatx4 z = {0.f, 0.f, 0.f, 0.f};
        floatx4 s[4];
        __builtin_amdgcn_s_setprio(1);
#pragma unroll
        for (int kg = 0; kg < 4; ++kg) {
            s[kg] = MFMA(aq[0], bk[kg][0], z);
            s[kg] = MFMA(aq[1], bk[kg][1], s[kg]);
        }
        __builtin_amdgcn_s_setprio(0);

        // two kh passes: exp+mask -> P tile -> drain -> PV (4 MFMAs each)
#pragma unroll
        for (int kh = 0; kh < 2; ++kh) {
            __bf16* pw = &pt[wave][0];
#pragma unroll
            for (int g2 = 0; g2 < 2; ++g2) {
                const int kj = k0 + (kh * 2 + g2) * 16 + col;
                const bool pre = kj < bp;
#pragma unroll
                for (int r = 0; r < 4; ++r) {
                    const int qi = q0 + quad * 4 + r;
                    float e = EXP2(s[kh * 2 + g2][r]);
                    float p = (pre || (kj <= qi)) ? e : 0.f;
                    ls[r] += p;
                    pw[(quad * 4 + r) * 40 + g2 * 16 + col] = (__bf16)p;
                }
            }
            __asm__ __volatile__("" ::: "memory");
            __builtin_amdgcn_s_waitcnt(0xC07F);   // lgkmcnt(0): P writes drained
            __asm__ __volatile__("" ::: "memory");
            bf16x8 ap = *(const bf16x8*)(&pt[wave][0] + col * 40 + quad * 8);
            __builtin_amdgcn_s_setprio(1);
#pragma unroll
            for (int f = 0; f < 4; ++f)
                o[f] = MFMA(ap, bv[f][kh], o[f]);
            __builtin_amdgcn_s_setprio(0);
            __asm__ __volatile__("" ::: "memory");  // next P writes stay behind ap
        }

        // rendezvous: own+partner DMA landed (vmcnt 0) and both waves done
        // reading buf cur (all ds_reads consumed by MFMAs above) -> safe to
        // overwrite next iteration.
        __syncthreads();
    }

    // epilogue: reduce l across the 16 col-lanes, normalize, plain stores
#pragma unroll
    for (int r = 0; r < 4; ++r) {
        float l = ls[r];
        l += __shfl_xor(l, 1);
        l += __shfl_xor(l, 2);
        l += __shfl_xor(l, 4);
        l += __shfl_xor(l, 8);
        const float inv = (l > 0.f) ? (1.f / l) : 0.f;
        const int row = q0 + quad * 4 + r;
        float* op = out + obase + (size_t)row * RS;
#pragma unroll
        for (int f = 0; f < 4; ++f)
            op[f * 16 + col] = o[f][r] * inv;
    }
}

extern "C" void kernel_launch(void* const* d_in, const int* in_sizes, int n_in,
                              void* d_out, int out_size, void* d_ws, size_t ws_size,
                              hipStream_t stream) {
    const float* q = (const float*)d_in[0];
    const float* k = (const float*)d_in[1];
    const float* v = (const float*)d_in[2];
    const int* glm = (const int*)d_in[3];
    float* out     = (float*)d_out;

    const size_t kb_bytes = (size_t)KB_ELEMS * 2;            // 8 MB
    __bf16* kbuf = (__bf16*)d_ws;
    __bf16* vbuf = (__bf16*)((char*)d_ws + kb_bytes);

    hipLaunchKernelGGL(conv_kv, dim3(1024), dim3(256), 0, stream,
                       k, v, kbuf, vbuf);
    // 64 q-tiles (LPT order) x 32 heads = 2048 two-wave blocks
    hipLaunchKernelGGL(fa_part11, dim3(2048), dim3(128), 0, stream,
                       q, kbuf, vbuf, glm, out);
}

// Round 10
// 161.802 us; speedup vs baseline: 1.7137x; 1.0738x over previous
//
#include <hip/hip_runtime.h>
#include <hip/hip_bf16.h>

// GLM flash attention fwd: b=2, s=2048, nh=16, hs=64, fp32 I/O, bf16 MFMA.
// R17: DMA pipeline + INDEPENDENT-wave TLP. R16 proved lockstep partner
// waves give zero TLP (94.5us = R15's 93.6 despite 2x occupancy); R15's
// 37.9KB LDS capped at 4 blocks/CU = 1 wave/SIMD. Cut LDS to ~19KB by
// removing the V LDS path: V B-frags load to REGISTERS via inline-asm
// global_load_dwordx4 (asm volatile cannot be latency-sunk - the R13/R14
// killer), issued at chunk top, covered by K ds_reads + 16 QK MFMAs,
// drained with COUNTED s_waitcnt vmcnt(8) (waits the 8 oldest = V; the 8
// K-DMA prefetch loads for c+1 stay in flight, m135 semantics) +
// sched_barrier(0) (rule #18). K path verbatim R15 (DMA + XOR swizzle,
// counter-verified conflict-free). pt per-rg (2.56KB, 2 lgkm drains/chunk).
// -> 8 one-wave blocks/CU = 2 independent waves/SIMD, zero barriers.
// Uniform full-chunk fast path skips mask compares (identical floats).
// No split-K, no atomics, in-register normalize, single store.

typedef __attribute__((ext_vector_type(8))) __bf16 bf16x8;
typedef __attribute__((ext_vector_type(4))) __bf16 bf16x4;
typedef __attribute__((ext_vector_type(4))) float floatx4;

#define S_LEN 2048
#define NH 16
#define HS 64
#define RS 1024                     // fp32 floats between seq positions
#define KB_ELEMS (2 * NH * S_LEN * HS)   // 4,194,304 bf16 = 8 MB
#define SCALE_LOG2E 0.18033688011112042f // 0.125 / ln(2)

#if __has_builtin(__builtin_amdgcn_exp2f)
#define EXP2(x) __builtin_amdgcn_exp2f(x)
#else
#define EXP2(x) exp2f(x)
#endif

#define MFMA(a, b, c) __builtin_amdgcn_mfma_f32_16x16x32_bf16(a, b, c, 0, 0, 0)

// async 16B global->LDS (no VGPR destination; vmcnt-counted)
#define GLOAD16(GP, LP)                                                        \
  __builtin_amdgcn_global_load_lds(                                            \
      (const __attribute__((address_space(1))) void*)(GP),                     \
      (__attribute__((address_space(3))) void*)(LP), 16, 0, 0)

// ---- pre-pass: K -> bf16 [b,h,s,d] (scaled), V -> bf16 V^T [b,h,d,s] ----
__global__ __launch_bounds__(256) void conv_kv(const float* __restrict__ k,
                                               const float* __restrict__ v,
                                               __bf16* __restrict__ kbuf,
                                               __bf16* __restrict__ vbuf)
{
    __shared__ __align__(16) __bf16 tile[64][72];     // [d][s], 144B rows
    const int tid = threadIdx.x;

    const int bh = blockIdx.x >> 5;                   // 32 s-tiles per (b,h)
    const int st = blockIdx.x & 31;
    const int b = bh >> 4, h = bh & 15;
    const int s0 = st * 64;

#pragma unroll
    for (int it = 0; it < 4; ++it) {
        const int idx = it * 256 + tid;
        const int s = idx >> 4, f4 = idx & 15;
        floatx4 val = *(const floatx4*)(k + ((size_t)(b * 2048 + s0 + s)) * 1024 + h * 64 + f4 * 4);
        bf16x4 w;
        w[0] = (__bf16)(val[0] * SCALE_LOG2E); w[1] = (__bf16)(val[1] * SCALE_LOG2E);
        w[2] = (__bf16)(val[2] * SCALE_LOG2E); w[3] = (__bf16)(val[3] * SCALE_LOG2E);
        *(bf16x4*)(kbuf + ((size_t)((b * 16 + h) * 2048 + s0 + s)) * 64 + f4 * 4) = w;
    }

#pragma unroll
    for (int it = 0; it < 4; ++it) {
        const int idx = it * 256 + tid;
        const int s = idx >> 4, f4 = idx & 15;
        floatx4 val = *(const floatx4*)(v + ((size_t)(b * 2048 + s0 + s)) * 1024 + h * 64 + f4 * 4);
#pragma unroll
        for (int i = 0; i < 4; ++i)
            tile[f4 * 4 + i][s] = (__bf16)val[i];
    }
    __syncthreads();
#pragma unroll
    for (int it = 0; it < 2; ++it) {
        const int idx = it * 256 + tid;
        const int d = idx >> 3, sg = idx & 7;
        bf16x8 w = *(const bf16x8*)&tile[d][sg * 8];
        *(bf16x8*)(vbuf + ((size_t)((b * 16 + h) * 64 + d)) * 2048 + s0 + sg * 8) = w;
    }
}

// ---- main kernel: 1 wave/block, 32 q-rows, K via DMA-LDS, V via asm-reg ----
__global__ __launch_bounds__(64, 2) void fa_part12(
    const float* __restrict__ q, const __bf16* __restrict__ kb,
    const __bf16* __restrict__ vt, const int* __restrict__ glm_mask,
    float* __restrict__ out)
{
    __shared__ __align__(16) __bf16 ldsK[2][64 * 64];   // 8KB/buf, linear rows
    __shared__ __align__(16) __bf16 pt[2][16 * 40];     // [rg], 2.56KB

    const int lane = threadIdx.x;                 // one wave per block
    const int col  = lane & 15, quad = lane >> 4;

    // LPT order: longest q-tiles first (q0 descending), heads fastest
    const int tile = blockIdx.x >> 5;             // 0..63
    const int head = blockIdx.x & 31;
    const int b = head >> 4, h = head & 15;
    const int q0 = (63 - tile) * 32;              // this wave's 32 q-rows

    const int bp = glm_mask[b];
    int klen = q0 + 32; if (bp > klen) klen = bp;
    const int nch = (klen + 63) >> 6;             // 1..32

    const __bf16* kbh = kb + ((size_t)(b * 16 + h)) * (2048 * 64);
    const __bf16* vth = vt + ((size_t)(b * 16 + h)) * (64 * 2048);
    const size_t obase = (size_t)b * (S_LEN * RS) + h * HS;

    // K staging geometry (R15-verified): DMA i covers rows i*8+rowi,
    // granule (lane&7)^rowi (source-side XOR swizzle).
    const int rowi = lane >> 3;                   // 0..7
    const int gswz = ((lane & 7) ^ rowi) << 4;    // source granule byte offset

#define STAGE_K(K0, NB)                                                        \
  {                                                                            \
    const char* gk = (const char*)kbh + (size_t)(K0) * 128;                    \
    _Pragma("unroll")                                                          \
    for (int i = 0; i < 8; ++i)                                                \
      GLOAD16(gk + (size_t)(i * 8 + rowi) * 128 + gswz, &ldsK[NB][i * 512]);   \
  }

    // V lane base: row d = f*16+col (stride 4096B), k-granule quad*8 (16B)
    const unsigned long long vlane =
        (unsigned long long)((const char*)vth + (size_t)col * 4096 + quad * 16);

    // Q A-frags: aq[rg][half], kd = half*32 + quad*8 + j
    bf16x8 aq[2][2];
#pragma unroll
    for (int rg = 0; rg < 2; ++rg) {
        const float* qp = q + obase + (size_t)(q0 + rg * 16 + col) * RS + quad * 8;
        floatx4 a0 = *(const floatx4*)qp;
        floatx4 a1 = *(const floatx4*)(qp + 4);
        floatx4 a2 = *(const floatx4*)(qp + 32);
        floatx4 a3 = *(const floatx4*)(qp + 36);
#pragma unroll
        for (int i = 0; i < 4; ++i) {
            aq[rg][0][i] = (__bf16)a0[i]; aq[rg][0][4 + i] = (__bf16)a1[i];
            aq[rg][1][i] = (__bf16)a2[i]; aq[rg][1][4 + i] = (__bf16)a3[i];
        }
    }

    floatx4 o[2][4];                // O C-frags: row = q0+rg*16+quad*4+r, d = f*16+col
    float ls[2][4];
#pragma unroll
    for (int rg = 0; rg < 2; ++rg)
#pragma unroll
        for (int f = 0; f < 4; ++f) {
            o[rg][f] = (floatx4){0.f, 0.f, 0.f, 0.f};
            ls[rg][f] = 0.f;
        }

    STAGE_K(0, 0);                  // prologue: K chunk 0 in flight

    const int cswz = (col & 7) << 4;   // read-side XOR, row&7 = col&7

// exp + mask -> pt (per rg); full-chunk fast path skips compares
#define EXP_WRITE(KH)                                                          \
  _Pragma("unroll")                                                            \
  for (int rg = 0; rg < 2; ++rg) {                                             \
    __bf16* pw = &pt[rg][0];                                                   \
    _Pragma("unroll")                                                          \
    for (int g2 = 0; g2 < 2; ++g2) {                                           \
      const int kj = k0 + ((KH) * 2 + g2) * 16 + col;                          \
      const bool pre = kj < bp;                                                \
      _Pragma("unroll")                                                        \
      for (int r = 0; r < 4; ++r) {                                            \
        float e = EXP2(s[rg][(KH) * 2 + g2][r]);                               \
        if (!full) {                                                           \
          const int qi = q0 + rg * 16 + quad * 4 + r;                          \
          if (!(pre || (kj <= qi))) e = 0.f;                                   \
        }                                                                      \
        ls[rg][r] += e;                                                        \
        pw[(quad * 4 + r) * 40 + g2 * 16 + col] = (__bf16)e;                   \
      }                                                                        \
    }                                                                          \
  }

#define PV_PASS(KH)                                                            \
  {                                                                            \
    __builtin_amdgcn_s_setprio(1);                                             \
    _Pragma("unroll")                                                          \
    for (int rg = 0; rg < 2; ++rg) {                                           \
      bf16x8 ap = *(const bf16x8*)(&pt[rg][0] + col * 40 + quad * 8);          \
      _Pragma("unroll")                                                        \
      for (int f = 0; f < 4; ++f)                                              \
        o[rg][f] = MFMA(ap, __builtin_bit_cast(bf16x8, bvr[f][KH]), o[rg][f]); \
    }                                                                          \
    __builtin_amdgcn_s_setprio(0);                                             \
    __asm__ __volatile__("" ::: "memory"); /* next pt writes stay behind ap */ \
  }

    for (int c = 0; c < nch; ++c) {
        const int k0 = c * 64;
        const int cur = c & 1;

        // K(c) DMA (and, first iter, Q loads) guaranteed landed
        __asm__ __volatile__("s_waitcnt vmcnt(0)" ::: "memory");

        // V(c) -> registers via inline asm (cannot be sunk); 8 oldest vm ops
        floatx4 bvr[4][2];
#pragma unroll
        for (int f = 0; f < 4; ++f)
#pragma unroll
            for (int kh = 0; kh < 2; ++kh) {
                unsigned long long va = vlane + (size_t)k0 * 2 + f * 65536 + kh * 64;
                __asm__ __volatile__("global_load_dwordx4 %0, %1, off"
                                     : "=v"(bvr[f][kh]) : "v"(va) : "memory");
            }

        // K frag reads from swizzled LDS (R15-verified conflict-free)
        const char* lK = (const char*)&ldsK[cur][0];
        bf16x8 bk[4][2];
#pragma unroll
        for (int kg = 0; kg < 4; ++kg)
#pragma unroll
            for (int hf = 0; hf < 2; ++hf)
                bk[kg][hf] = *(const bf16x8*)(lK + (kg * 16 + col) * 128 + ((hf * 64 + quad * 16) ^ cswz));

        // issue K(c+1) DMA into the other buffer (stays in flight through PV)
        if (c + 1 < nch)
            STAGE_K(k0 + 64, cur ^ 1);

        // QK^T (K carries 0.125*log2e): 16 MFMAs
        floatx4 z = {0.f, 0.f, 0.f, 0.f};
        floatx4 s[2][4];
        __builtin_amdgcn_s_setprio(1);
#pragma unroll
        for (int rg = 0; rg < 2; ++rg)
#pragma unroll
            for (int kg = 0; kg < 4; ++kg) {
                s[rg][kg] = MFMA(aq[rg][0], bk[kg][0], z);
                s[rg][kg] = MFMA(aq[rg][1], bk[kg][1], s[rg][kg]);
            }
        __builtin_amdgcn_s_setprio(0);

        const bool full = (k0 + 63 < bp) || (k0 + 63 <= q0);

        // kh = 0: exp/mask -> pt; drain pt writes AND the 8 V loads (counted:
        // the 8 K-DMA prefetch ops stay in flight); then PV.
        EXP_WRITE(0);
        if (c + 1 < nch) {
            __asm__ __volatile__("s_waitcnt vmcnt(8) lgkmcnt(0)" ::: "memory");
        } else {
            __asm__ __volatile__("s_waitcnt vmcnt(0) lgkmcnt(0)" ::: "memory");
        }
        __builtin_amdgcn_sched_barrier(0);   // rule #18: pin MFMAs behind waits
        PV_PASS(0);

        // kh = 1: same pt buffers (in-order DS per wave -> WAR-safe)
        EXP_WRITE(1);
        __asm__ __volatile__("s_waitcnt lgkmcnt(0)" ::: "memory");
        __builtin_amdgcn_sched_barrier(0);
        PV_PASS(1);
    }

    // epilogue: reduce l across the 16 col-lanes, normalize, plain stores
#pragma unroll
    for (int rg = 0; rg < 2; ++rg)
#pragma unroll
        for (int r = 0; r < 4; ++r) {
            float l = ls[rg][r];
            l += __shfl_xor(l, 1);
            l += __shfl_xor(l, 2);
            l += __shfl_xor(l, 4);
            l += __shfl_xor(l, 8);
            const float inv = (l > 0.f) ? (1.f / l) : 0.f;
            const int row = q0 + rg * 16 + quad * 4 + r;
            float* op = out + obase + (size_t)row * RS;
#pragma unroll
            for (int f = 0; f < 4; ++f)
                op[f * 16 + col] = o[rg][f][r] * inv;
        }
}

extern "C" void kernel_launch(void* const* d_in, const int* in_sizes, int n_in,
                              void* d_out, int out_size, void* d_ws, size_t ws_size,
                              hipStream_t stream) {
    const float* q = (const float*)d_in[0];
    const float* k = (const float*)d_in[1];
    const float* v = (const float*)d_in[2];
    const int* glm = (const int*)d_in[3];
    float* out     = (float*)d_out;

    const size_t kb_bytes = (size_t)KB_ELEMS * 2;            // 8 MB
    __bf16* kbuf = (__bf16*)d_ws;
    __bf16* vbuf = (__bf16*)((char*)d_ws + kb_bytes);

    hipLaunchKernelGGL(conv_kv, dim3(1024), dim3(256), 0, stream,
                       k, v, kbuf, vbuf);
    // 64 q-tiles (LPT order) x 32 heads = 2048 one-wave blocks (8/CU)
    hipLaunchKernelGGL(fa_part12, dim3(2048), dim3(64), 0, stream,
                       q, kbuf, vbuf, glm, out);
}